// Round 6
// baseline (333.457 us; speedup 1.0000x reference)
//
#include <hip/hip_runtime.h>
#include <hip/hip_bf16.h>

typedef float  f32x2  __attribute__((ext_vector_type(2)));
typedef float  f32x4  __attribute__((ext_vector_type(4)));
typedef short  bf16x8 __attribute__((ext_vector_type(8)));

#define HEADS 8
#define HID 64
#define IN_NODE 128
#define IN_EDGE 64
#define LDSP 68   // LDS row pad: 68 words = 272B, 16B-aligned

// f32 -> bf16 (RNE), as raw bits in a short
static __device__ __forceinline__ short f2bf(float f) {
    unsigned u = __builtin_bit_cast(unsigned, f);
    unsigned r = (u + 0x7FFFu + ((u >> 16) & 1u)) >> 16;
    return (short)r;
}

// ---------------------------------------------------------------------------
// QKV projection via MFMA (verified correct in R3/R5).
// ---------------------------------------------------------------------------
__global__ __launch_bounds__(256, 4) void qkv_kernel(
    const float* __restrict__ h,
    const float* __restrict__ WQ, const float* __restrict__ bQ,
    const float* __restrict__ WK, const float* __restrict__ bK,
    const float* __restrict__ WV, const float* __restrict__ bV,
    float* __restrict__ Q, float* __restrict__ K, float* __restrict__ V,
    int n_nodes)
{
    const int lane = threadIdx.x & 63;
    const int r16  = lane & 15;
    const int g4   = lane >> 4;
    const int wave   = blockIdx.x * (blockDim.x >> 6) + (threadIdx.x >> 6);
    const int nwaves = gridDim.x * (blockDim.x >> 6);
    const int mat  = blockIdx.y;

    const float* __restrict__ W  = (mat == 0) ? WQ : (mat == 1) ? WK : WV;
    const float* __restrict__ bp = (mat == 0) ? bQ : (mat == 1) ? bK : bV;
    float* __restrict__ out      = (mat == 0) ? Q  : (mat == 1) ? K  : V;

    bf16x8 bfr[4][4];
#pragma unroll
    for (int ct = 0; ct < 4; ++ct)
#pragma unroll
        for (int kc = 0; kc < 4; ++kc)
#pragma unroll
            for (int j = 0; j < 8; ++j) {
                int k = kc * 32 + g4 * 8 + j;
                bfr[ct][kc][j] = f2bf(W[k * HID + ct * 16 + r16]);
            }
    float bias[4];
#pragma unroll
    for (int ct = 0; ct < 4; ++ct) bias[ct] = bp[ct * 16 + r16];

    const int ntiles = (n_nodes + 15) >> 4;
    for (int tile = wave; tile < ntiles; tile += nwaves) {
        const int row0 = tile * 16;
        int arow = row0 + r16; if (arow > n_nodes - 1) arow = n_nodes - 1;
        const float* ap = h + (size_t)arow * IN_NODE + g4 * 8;

        bf16x8 afr[4];
#pragma unroll
        for (int kc = 0; kc < 4; ++kc) {
            f32x4 p0 = *reinterpret_cast<const f32x4*>(ap + kc * 32);
            f32x4 p1 = *reinterpret_cast<const f32x4*>(ap + kc * 32 + 4);
            afr[kc][0] = f2bf(p0.x); afr[kc][1] = f2bf(p0.y);
            afr[kc][2] = f2bf(p0.z); afr[kc][3] = f2bf(p0.w);
            afr[kc][4] = f2bf(p1.x); afr[kc][5] = f2bf(p1.y);
            afr[kc][6] = f2bf(p1.z); afr[kc][7] = f2bf(p1.w);
        }

        f32x4 acc[4] = {};
#pragma unroll
        for (int ct = 0; ct < 4; ++ct)
#pragma unroll
            for (int kc = 0; kc < 4; ++kc)
                acc[ct] = __builtin_amdgcn_mfma_f32_16x16x32_bf16(
                    afr[kc], bfr[ct][kc], acc[ct], 0, 0, 0);

#pragma unroll
        for (int ct = 0; ct < 4; ++ct)
#pragma unroll
            for (int r = 0; r < 4; ++r) {
                int orow = row0 + g4 * 4 + r;
                if (orow < n_nodes)
                    out[(size_t)orow * HID + ct * 16 + r16] = acc[ct][r] + bias[ct];
            }
    }
}

// ---------------------------------------------------------------------------
// Edge kernel (pure streaming — NO atomics): MFMA pe = e @ We, LDS lane
// remap, score -> e_out (NT), per-head exp -> a[E,8] (normal store, L3-hot
// for zpass). vmcnt FIFO no longer gated by atomic acks.
// ---------------------------------------------------------------------------
__global__ __launch_bounds__(256, 4) void edge_kernel(
    const int* __restrict__ ei, const float* __restrict__ e,
    const float* __restrict__ We, const float* __restrict__ be,
    const float* __restrict__ Q, const float* __restrict__ K,
    float* __restrict__ e_out, float* __restrict__ aws, int n_edges)
{
    const int lane = threadIdx.x & 63;
    const int wid  = threadIdx.x >> 6;
    const int r16  = lane & 15;
    const int g4   = lane >> 4;
    const int el   = lane >> 2;   // epilogue: edge-local 0..15
    const int qg   = lane & 3;    // epilogue: col-quad 0..3

    __shared__ float plds[4][16][LDSP];
    float (*my)[LDSP] = plds[wid];

    const int wave   = blockIdx.x * 4 + wid;
    const int nwaves = gridDim.x * 4;

    bf16x8 bfr[4][2];
#pragma unroll
    for (int ct = 0; ct < 4; ++ct)
#pragma unroll
        for (int kc = 0; kc < 2; ++kc)
#pragma unroll
            for (int j = 0; j < 8; ++j) {
                int k = kc * 32 + g4 * 8 + j;
                bfr[ct][kc][j] = f2bf(We[k * HID + ct * 16 + r16]);
            }
    float bias[4];
#pragma unroll
    for (int ct = 0; ct < 4; ++ct) bias[ct] = be[ct * 16 + r16];

    const float SC = 0.35355339059327373f;
    const int ntiles = (n_edges + 15) >> 4;
    for (int tile = wave; tile < ntiles; tile += nwaves) {
        const int e0 = tile * 16;

        // ---- A-frag: 16 e-rows, f32 -> bf16 (NT: streamed once)
        int arow = e0 + r16; if (arow > n_edges - 1) arow = n_edges - 1;
        const float* ap = e + (size_t)arow * IN_EDGE + g4 * 8;
        f32x4 p0a = __builtin_nontemporal_load(reinterpret_cast<const f32x4*>(ap));
        f32x4 p1a = __builtin_nontemporal_load(reinterpret_cast<const f32x4*>(ap + 4));
        f32x4 p0b = __builtin_nontemporal_load(reinterpret_cast<const f32x4*>(ap + 32));
        f32x4 p1b = __builtin_nontemporal_load(reinterpret_cast<const f32x4*>(ap + 36));

        bf16x8 afr[2];
        afr[0][0] = f2bf(p0a.x); afr[0][1] = f2bf(p0a.y);
        afr[0][2] = f2bf(p0a.z); afr[0][3] = f2bf(p0a.w);
        afr[0][4] = f2bf(p1a.x); afr[0][5] = f2bf(p1a.y);
        afr[0][6] = f2bf(p1a.z); afr[0][7] = f2bf(p1a.w);
        afr[1][0] = f2bf(p0b.x); afr[1][1] = f2bf(p0b.y);
        afr[1][2] = f2bf(p0b.z); afr[1][3] = f2bf(p0b.w);
        afr[1][4] = f2bf(p1b.x); afr[1][5] = f2bf(p1b.y);
        afr[1][6] = f2bf(p1b.z); afr[1][7] = f2bf(p1b.w);

        f32x4 acc[4] = {};
#pragma unroll
        for (int ct = 0; ct < 4; ++ct) {
            acc[ct] = __builtin_amdgcn_mfma_f32_16x16x32_bf16(afr[0], bfr[ct][0], acc[ct], 0, 0, 0);
            acc[ct] = __builtin_amdgcn_mfma_f32_16x16x32_bf16(afr[1], bfr[ct][1], acc[ct], 0, 0, 0);
        }

        // ---- pe + bias -> LDS
#pragma unroll
        for (int ct = 0; ct < 4; ++ct)
#pragma unroll
            for (int r = 0; r < 4; ++r)
                my[g4 * 4 + r][ct * 16 + r16] = acc[ct][r] + bias[ct];

        // ---- epilogue lane remap: (el, qg)
        int erow = e0 + el;
        bool valid = erow < n_edges;
        int erc = valid ? erow : n_edges - 1;
        int src = ei[erc];
        int dst = ei[n_edges + erc];

        const float* Kp = K + (size_t)src * HID + qg * 16;
        const float* Qp = Q + (size_t)dst * HID + qg * 16;
        f32x4 k0 = *reinterpret_cast<const f32x4*>(Kp);
        f32x4 k1 = *reinterpret_cast<const f32x4*>(Kp + 4);
        f32x4 k2 = *reinterpret_cast<const f32x4*>(Kp + 8);
        f32x4 k3 = *reinterpret_cast<const f32x4*>(Kp + 12);
        f32x4 q0 = *reinterpret_cast<const f32x4*>(Qp);
        f32x4 q1 = *reinterpret_cast<const f32x4*>(Qp + 4);
        f32x4 q2 = *reinterpret_cast<const f32x4*>(Qp + 8);
        f32x4 q3 = *reinterpret_cast<const f32x4*>(Qp + 12);

        // LDS handoff: same-wave DS ordering + explicit wait
        asm volatile("s_waitcnt lgkmcnt(0)" ::: "memory");
        const float* mrow = &my[el][qg * 16];
        f32x4 p0 = *reinterpret_cast<const f32x4*>(mrow);
        f32x4 p1 = *reinterpret_cast<const f32x4*>(mrow + 4);
        f32x4 p2 = *reinterpret_cast<const f32x4*>(mrow + 8);
        f32x4 p3 = *reinterpret_cast<const f32x4*>(mrow + 12);

        f32x4 s0 = k0 * q0 * SC + p0;
        f32x4 s1 = k1 * q1 * SC + p1;
        f32x4 s2 = k2 * q2 * SC + p2;
        f32x4 s3 = k3 * q3 * SC + p3;

        // lane owns heads 2qg and 2qg+1 fully: in-register reductions
        float hs0 = ((s0.x + s0.y) + (s0.z + s0.w)) + ((s1.x + s1.y) + (s1.z + s1.w));
        float hs1 = ((s2.x + s2.y) + (s2.z + s2.w)) + ((s3.x + s3.y) + (s3.z + s3.w));
        float a0 = __expf(fminf(fmaxf(hs0, -5.0f), 5.0f));
        float a1 = __expf(fminf(fmaxf(hs1, -5.0f), 5.0f));

        if (valid) {
            float* op = e_out + (size_t)erow * HID + qg * 16;
            __builtin_nontemporal_store(s0, reinterpret_cast<f32x4*>(op));
            __builtin_nontemporal_store(s1, reinterpret_cast<f32x4*>(op + 4));
            __builtin_nontemporal_store(s2, reinterpret_cast<f32x4*>(op + 8));
            __builtin_nontemporal_store(s3, reinterpret_cast<f32x4*>(op + 12));
            // a[edge][2qg..2qg+1] — 8B/lane, contiguous 32B/edge (L3-hot)
            f32x2 av = {a0, a1};
            *reinterpret_cast<f32x2*>(aws + (size_t)erow * HEADS + qg * 2) = av;
        }
    }
}

// ---------------------------------------------------------------------------
// Z-pass: thread = (edge, head). Reads a[E,8] (L3-hot) and scatters into
// z_sum / cnt. Unroll-4: all loads issued before the atomic batch so vmcnt
// FIFO stalls amortize; atomics are mutually independent.
// ---------------------------------------------------------------------------
__global__ __launch_bounds__(256) void zpass_kernel(
    const int* __restrict__ ei, const float* __restrict__ aws,
    float* __restrict__ z_sum, float* __restrict__ cnt, int n_edges)
{
    const int tid  = blockIdx.x * 256 + threadIdx.x;
    const int nthr = gridDim.x * 256;
    const int head = tid & 7;
    const int eg   = tid >> 3;
    const int estr = nthr >> 3;

    int edge = eg;
    for (; edge + 3 * estr < n_edges; edge += 4 * estr) {
        int e0 = edge, e1 = edge + estr, e2 = edge + 2 * estr, e3 = edge + 3 * estr;
        int s0 = ei[e0], s1 = ei[e1], s2 = ei[e2], s3 = ei[e3];
        float v0 = aws[(size_t)e0 * HEADS + head];
        float v1 = aws[(size_t)e1 * HEADS + head];
        float v2 = aws[(size_t)e2 * HEADS + head];
        float v3 = aws[(size_t)e3 * HEADS + head];
        atomicAdd(&z_sum[s0 * HEADS + head], v0);
        atomicAdd(&z_sum[s1 * HEADS + head], v1);
        atomicAdd(&z_sum[s2 * HEADS + head], v2);
        atomicAdd(&z_sum[s3 * HEADS + head], v3);
        if (head == 0) {
            atomicAdd(&cnt[s0], 1.0f);
            atomicAdd(&cnt[s1], 1.0f);
            atomicAdd(&cnt[s2], 1.0f);
            atomicAdd(&cnt[s3], 1.0f);
        }
    }
    for (; edge < n_edges; edge += estr) {
        int s = ei[edge];
        float v = aws[(size_t)edge * HEADS + head];
        atomicAdd(&z_sum[s * HEADS + head], v);
        if (head == 0) atomicAdd(&cnt[s], 1.0f);
    }
}

// ---------------------------------------------------------------------------
// Finalize: h_out[n,h,d] = V[n,h,d]*S / (S/max(cnt,1) + 1e-6)
// ---------------------------------------------------------------------------
__global__ __launch_bounds__(256) void finalize_kernel(
    const float* __restrict__ V, const float* __restrict__ z_sum,
    const float* __restrict__ cnt, float* __restrict__ h_out, int total)
{
    int i = blockIdx.x * 256 + threadIdx.x;
    if (i >= total) return;
    int node = i >> 6;
    int head = (i >> 3) & 7;
    float S = z_sum[node * HEADS + head];
    float c = fmaxf(cnt[node], 1.0f);
    h_out[i] = V[i] * S / (S / c + 1e-6f);
}

extern "C" void kernel_launch(void* const* d_in, const int* in_sizes, int n_in,
                              void* d_out, int out_size, void* d_ws, size_t ws_size,
                              hipStream_t stream)
{
    const int*   ei = (const int*)d_in[0];
    const float* h  = (const float*)d_in[1];
    const float* e  = (const float*)d_in[2];
    const float* WQ = (const float*)d_in[3];
    const float* bQ = (const float*)d_in[4];
    const float* WK = (const float*)d_in[5];
    const float* bK = (const float*)d_in[6];
    const float* WV = (const float*)d_in[7];
    const float* bV = (const float*)d_in[8];
    const float* We = (const float*)d_in[9];
    const float* be = (const float*)d_in[10];

    const int n_nodes = in_sizes[1] / IN_NODE;   // 50000
    const int n_edges = in_sizes[2] / IN_EDGE;   // 800000

    float* out_h = (float*)d_out;                       // n_nodes*64
    float* out_e = out_h + (size_t)n_nodes * HID;       // n_edges*64

    float* Q     = (float*)d_ws;
    float* K     = Q + (size_t)n_nodes * HID;
    float* V     = K + (size_t)n_nodes * HID;
    float* z_sum = V + (size_t)n_nodes * HID;
    float* cnt   = z_sum + (size_t)n_nodes * HEADS;
    float* aws   = cnt + (size_t)n_nodes;               // a[E,8]: 25.6 MB

    (void)hipMemsetAsync(z_sum, 0, (size_t)n_nodes * (HEADS + 1) * sizeof(float), stream);

    // QKV: 96 blocks x 4 waves x 3 mats
    {
        dim3 grid(96, 3);
        qkv_kernel<<<grid, 256, 0, stream>>>(h, WQ, bQ, WK, bK, WV, bV,
                                             Q, K, V, n_nodes);
    }
    // Edge: pure streaming
    {
        edge_kernel<<<2048, 256, 0, stream>>>(ei, e, We, be, Q, K,
                                              out_e, aws, n_edges);
    }
    // Z-pass: scatter-reduce a into z_sum / cnt
    {
        zpass_kernel<<<2048, 256, 0, stream>>>(ei, aws, z_sum, cnt, n_edges);
    }
    // Finalize
    {
        const int total = n_nodes * HID;
        finalize_kernel<<<(total + 255) / 256, 256, 0, stream>>>(V, z_sum, cnt,
                                                                 out_h, total);
    }
}

// Round 7
// 240.630 us; speedup vs baseline: 1.3858x; 1.3858x over previous
//
#include <hip/hip_runtime.h>
#include <hip/hip_bf16.h>

typedef float  f32x2  __attribute__((ext_vector_type(2)));
typedef float  f32x4  __attribute__((ext_vector_type(4)));
typedef short  bf16x8 __attribute__((ext_vector_type(8)));

#define HEADS 8
#define HID 64
#define IN_NODE 128
#define IN_EDGE 64
#define LDSP 68   // LDS row pad: 68 words = 272B, 16B-aligned

// f32 -> bf16 (RNE), as raw bits in a short
static __device__ __forceinline__ short f2bf(float f) {
    unsigned u = __builtin_bit_cast(unsigned, f);
    unsigned r = (u + 0x7FFFu + ((u >> 16) & 1u)) >> 16;
    return (short)r;
}

// ---------------------------------------------------------------------------
// QKV projection via MFMA (verified correct R3/R5/R6).
// ---------------------------------------------------------------------------
__global__ __launch_bounds__(256, 4) void qkv_kernel(
    const float* __restrict__ h,
    const float* __restrict__ WQ, const float* __restrict__ bQ,
    const float* __restrict__ WK, const float* __restrict__ bK,
    const float* __restrict__ WV, const float* __restrict__ bV,
    float* __restrict__ Q, float* __restrict__ K, float* __restrict__ V,
    int n_nodes)
{
    const int lane = threadIdx.x & 63;
    const int r16  = lane & 15;
    const int g4   = lane >> 4;
    const int wave   = blockIdx.x * (blockDim.x >> 6) + (threadIdx.x >> 6);
    const int nwaves = gridDim.x * (blockDim.x >> 6);
    const int mat  = blockIdx.y;

    const float* __restrict__ W  = (mat == 0) ? WQ : (mat == 1) ? WK : WV;
    const float* __restrict__ bp = (mat == 0) ? bQ : (mat == 1) ? bK : bV;
    float* __restrict__ out      = (mat == 0) ? Q  : (mat == 1) ? K  : V;

    bf16x8 bfr[4][4];
#pragma unroll
    for (int ct = 0; ct < 4; ++ct)
#pragma unroll
        for (int kc = 0; kc < 4; ++kc)
#pragma unroll
            for (int j = 0; j < 8; ++j) {
                int k = kc * 32 + g4 * 8 + j;
                bfr[ct][kc][j] = f2bf(W[k * HID + ct * 16 + r16]);
            }
    float bias[4];
#pragma unroll
    for (int ct = 0; ct < 4; ++ct) bias[ct] = bp[ct * 16 + r16];

    const int ntiles = (n_nodes + 15) >> 4;
    for (int tile = wave; tile < ntiles; tile += nwaves) {
        const int row0 = tile * 16;
        int arow = row0 + r16; if (arow > n_nodes - 1) arow = n_nodes - 1;
        const float* ap = h + (size_t)arow * IN_NODE + g4 * 8;

        bf16x8 afr[4];
#pragma unroll
        for (int kc = 0; kc < 4; ++kc) {
            f32x4 p0 = *reinterpret_cast<const f32x4*>(ap + kc * 32);
            f32x4 p1 = *reinterpret_cast<const f32x4*>(ap + kc * 32 + 4);
            afr[kc][0] = f2bf(p0.x); afr[kc][1] = f2bf(p0.y);
            afr[kc][2] = f2bf(p0.z); afr[kc][3] = f2bf(p0.w);
            afr[kc][4] = f2bf(p1.x); afr[kc][5] = f2bf(p1.y);
            afr[kc][6] = f2bf(p1.z); afr[kc][7] = f2bf(p1.w);
        }

        f32x4 acc[4] = {};
#pragma unroll
        for (int ct = 0; ct < 4; ++ct)
#pragma unroll
            for (int kc = 0; kc < 4; ++kc)
                acc[ct] = __builtin_amdgcn_mfma_f32_16x16x32_bf16(
                    afr[kc], bfr[ct][kc], acc[ct], 0, 0, 0);

#pragma unroll
        for (int ct = 0; ct < 4; ++ct)
#pragma unroll
            for (int r = 0; r < 4; ++r) {
                int orow = row0 + g4 * 4 + r;
                if (orow < n_nodes)
                    out[(size_t)orow * HID + ct * 16 + r16] = acc[ct][r] + bias[ct];
            }
    }
}

// ---------------------------------------------------------------------------
// Edge kernel (R5 structure, NO nontemporal): MFMA pe = e @ We, LDS lane
// remap, score -> e_out (plain stores -> L2 write-combining merges the
// 16B/64B-strided pattern into full lines), per-head exp -> inline atomics
// (proven free when overlapped with the stream, R5 vs R6).
// ---------------------------------------------------------------------------
__global__ __launch_bounds__(256, 4) void edge_kernel(
    const int* __restrict__ ei, const float* __restrict__ e,
    const float* __restrict__ We, const float* __restrict__ be,
    const float* __restrict__ Q, const float* __restrict__ K,
    float* __restrict__ e_out, float* __restrict__ z_sum,
    float* __restrict__ cnt, int n_edges)
{
    const int lane = threadIdx.x & 63;
    const int wid  = threadIdx.x >> 6;
    const int r16  = lane & 15;
    const int g4   = lane >> 4;
    const int el   = lane >> 2;   // epilogue: edge-local 0..15
    const int qg   = lane & 3;    // epilogue: col-quad 0..3

    __shared__ float plds[4][16][LDSP];
    float (*my)[LDSP] = plds[wid];

    const int wave   = blockIdx.x * 4 + wid;
    const int nwaves = gridDim.x * 4;

    bf16x8 bfr[4][2];
#pragma unroll
    for (int ct = 0; ct < 4; ++ct)
#pragma unroll
        for (int kc = 0; kc < 2; ++kc)
#pragma unroll
            for (int j = 0; j < 8; ++j) {
                int k = kc * 32 + g4 * 8 + j;
                bfr[ct][kc][j] = f2bf(We[k * HID + ct * 16 + r16]);
            }
    float bias[4];
#pragma unroll
    for (int ct = 0; ct < 4; ++ct) bias[ct] = be[ct * 16 + r16];

    const float SC = 0.35355339059327373f;
    const int ntiles = (n_edges + 15) >> 4;
    for (int tile = wave; tile < ntiles; tile += nwaves) {
        const int e0 = tile * 16;

        // ---- A-frag: 16 e-rows, f32 -> bf16
        int arow = e0 + r16; if (arow > n_edges - 1) arow = n_edges - 1;
        const float* ap = e + (size_t)arow * IN_EDGE + g4 * 8;
        f32x4 p0a = *reinterpret_cast<const f32x4*>(ap);
        f32x4 p1a = *reinterpret_cast<const f32x4*>(ap + 4);
        f32x4 p0b = *reinterpret_cast<const f32x4*>(ap + 32);
        f32x4 p1b = *reinterpret_cast<const f32x4*>(ap + 36);

        bf16x8 afr[2];
        afr[0][0] = f2bf(p0a.x); afr[0][1] = f2bf(p0a.y);
        afr[0][2] = f2bf(p0a.z); afr[0][3] = f2bf(p0a.w);
        afr[0][4] = f2bf(p1a.x); afr[0][5] = f2bf(p1a.y);
        afr[0][6] = f2bf(p1a.z); afr[0][7] = f2bf(p1a.w);
        afr[1][0] = f2bf(p0b.x); afr[1][1] = f2bf(p0b.y);
        afr[1][2] = f2bf(p0b.z); afr[1][3] = f2bf(p0b.w);
        afr[1][4] = f2bf(p1b.x); afr[1][5] = f2bf(p1b.y);
        afr[1][6] = f2bf(p1b.z); afr[1][7] = f2bf(p1b.w);

        f32x4 acc[4] = {};
#pragma unroll
        for (int ct = 0; ct < 4; ++ct) {
            acc[ct] = __builtin_amdgcn_mfma_f32_16x16x32_bf16(afr[0], bfr[ct][0], acc[ct], 0, 0, 0);
            acc[ct] = __builtin_amdgcn_mfma_f32_16x16x32_bf16(afr[1], bfr[ct][1], acc[ct], 0, 0, 0);
        }

        // ---- pe + bias -> LDS
#pragma unroll
        for (int ct = 0; ct < 4; ++ct)
#pragma unroll
            for (int r = 0; r < 4; ++r)
                my[g4 * 4 + r][ct * 16 + r16] = acc[ct][r] + bias[ct];

        // ---- epilogue lane remap: (el, qg)
        int erow = e0 + el;
        bool valid = erow < n_edges;
        int erc = valid ? erow : n_edges - 1;
        int src = ei[erc];
        int dst = ei[n_edges + erc];

        const float* Kp = K + (size_t)src * HID + qg * 16;
        const float* Qp = Q + (size_t)dst * HID + qg * 16;
        f32x4 k0 = *reinterpret_cast<const f32x4*>(Kp);
        f32x4 k1 = *reinterpret_cast<const f32x4*>(Kp + 4);
        f32x4 k2 = *reinterpret_cast<const f32x4*>(Kp + 8);
        f32x4 k3 = *reinterpret_cast<const f32x4*>(Kp + 12);
        f32x4 q0 = *reinterpret_cast<const f32x4*>(Qp);
        f32x4 q1 = *reinterpret_cast<const f32x4*>(Qp + 4);
        f32x4 q2 = *reinterpret_cast<const f32x4*>(Qp + 8);
        f32x4 q3 = *reinterpret_cast<const f32x4*>(Qp + 12);

        // LDS handoff: same-wave DS ordering + explicit wait
        asm volatile("s_waitcnt lgkmcnt(0)" ::: "memory");
        const float* mrow = &my[el][qg * 16];
        f32x4 p0 = *reinterpret_cast<const f32x4*>(mrow);
        f32x4 p1 = *reinterpret_cast<const f32x4*>(mrow + 4);
        f32x4 p2 = *reinterpret_cast<const f32x4*>(mrow + 8);
        f32x4 p3 = *reinterpret_cast<const f32x4*>(mrow + 12);

        f32x4 s0 = k0 * q0 * SC + p0;
        f32x4 s1 = k1 * q1 * SC + p1;
        f32x4 s2 = k2 * q2 * SC + p2;
        f32x4 s3 = k3 * q3 * SC + p3;

        if (valid) {
            float* op = e_out + (size_t)erow * HID + qg * 16;
            *reinterpret_cast<f32x4*>(op)      = s0;
            *reinterpret_cast<f32x4*>(op + 4)  = s1;
            *reinterpret_cast<f32x4*>(op + 8)  = s2;
            *reinterpret_cast<f32x4*>(op + 12) = s3;
        }

        // lane owns heads 2qg and 2qg+1 fully: in-register reductions
        float hs0 = ((s0.x + s0.y) + (s0.z + s0.w)) + ((s1.x + s1.y) + (s1.z + s1.w));
        float hs1 = ((s2.x + s2.y) + (s2.z + s2.w)) + ((s3.x + s3.y) + (s3.z + s3.w));
        float a0 = __expf(fminf(fmaxf(hs0, -5.0f), 5.0f));
        float a1 = __expf(fminf(fmaxf(hs1, -5.0f), 5.0f));
        if (valid) {
            atomicAdd(&z_sum[src * HEADS + qg * 2], a0);
            atomicAdd(&z_sum[src * HEADS + qg * 2 + 1], a1);
            if (qg == 0) atomicAdd(&cnt[src], 1.0f);
        }
    }
}

// ---------------------------------------------------------------------------
// Finalize: h_out[n,h,d] = V[n,h,d]*S / (S/max(cnt,1) + 1e-6)
// ---------------------------------------------------------------------------
__global__ __launch_bounds__(256) void finalize_kernel(
    const float* __restrict__ V, const float* __restrict__ z_sum,
    const float* __restrict__ cnt, float* __restrict__ h_out, int total)
{
    int i = blockIdx.x * 256 + threadIdx.x;
    if (i >= total) return;
    int node = i >> 6;
    int head = (i >> 3) & 7;
    float S = z_sum[node * HEADS + head];
    float c = fmaxf(cnt[node], 1.0f);
    h_out[i] = V[i] * S / (S / c + 1e-6f);
}

extern "C" void kernel_launch(void* const* d_in, const int* in_sizes, int n_in,
                              void* d_out, int out_size, void* d_ws, size_t ws_size,
                              hipStream_t stream)
{
    const int*   ei = (const int*)d_in[0];
    const float* h  = (const float*)d_in[1];
    const float* e  = (const float*)d_in[2];
    const float* WQ = (const float*)d_in[3];
    const float* bQ = (const float*)d_in[4];
    const float* WK = (const float*)d_in[5];
    const float* bK = (const float*)d_in[6];
    const float* WV = (const float*)d_in[7];
    const float* bV = (const float*)d_in[8];
    const float* We = (const float*)d_in[9];
    const float* be = (const float*)d_in[10];

    const int n_nodes = in_sizes[1] / IN_NODE;   // 50000
    const int n_edges = in_sizes[2] / IN_EDGE;   // 800000

    float* out_h = (float*)d_out;                       // n_nodes*64
    float* out_e = out_h + (size_t)n_nodes * HID;       // n_edges*64

    float* Q     = (float*)d_ws;
    float* K     = Q + (size_t)n_nodes * HID;
    float* V     = K + (size_t)n_nodes * HID;
    float* z_sum = V + (size_t)n_nodes * HID;
    float* cnt   = z_sum + (size_t)n_nodes * HEADS;

    (void)hipMemsetAsync(z_sum, 0, (size_t)n_nodes * (HEADS + 1) * sizeof(float), stream);

    // QKV: 96 blocks x 4 waves x 3 mats
    {
        dim3 grid(96, 3);
        qkv_kernel<<<grid, 256, 0, stream>>>(h, WQ, bQ, WK, bK, WV, bV,
                                             Q, K, V, n_nodes);
    }
    // Edge: streaming + inline atomics
    {
        edge_kernel<<<2048, 256, 0, stream>>>(ei, e, We, be, Q, K,
                                              out_e, z_sum, cnt, n_edges);
    }
    // Finalize
    {
        const int total = n_nodes * HID;
        finalize_kernel<<<(total + 255) / 256, 256, 0, stream>>>(V, z_sum, cnt,
                                                                 out_h, total);
    }
}

// Round 8
// 222.339 us; speedup vs baseline: 1.4998x; 1.0823x over previous
//
#include <hip/hip_runtime.h>
#include <hip/hip_bf16.h>

typedef float        f32x4  __attribute__((ext_vector_type(4)));
typedef short        bf16x8 __attribute__((ext_vector_type(8)));
typedef unsigned int u32x4  __attribute__((ext_vector_type(4)));

#define HEADS 8
#define HID 64
#define IN_NODE 128
#define IN_EDGE 64
#define LDSP 69   // 69 words/row: conflict-free b128 epilogue reads, 2-way writes

// f32 -> bf16 (RNE), as raw bits in a short
static __device__ __forceinline__ short f2bf(float f) {
    unsigned u = __builtin_bit_cast(unsigned, f);
    unsigned r = (u + 0x7FFFu + ((u >> 16) & 1u)) >> 16;
    return (short)r;
}
static __device__ __forceinline__ float bflo(unsigned u) {
    return __builtin_bit_cast(float, u << 16);
}
static __device__ __forceinline__ float bfhi(unsigned u) {
    return __builtin_bit_cast(float, u & 0xFFFF0000u);
}

// ---------------------------------------------------------------------------
// QKV projection via MFMA. Q,K written as bf16 (K pre-scaled by 1/sqrt(8)),
// V stays f32 (needed in f32 for finalize).
// ---------------------------------------------------------------------------
__global__ __launch_bounds__(256, 4) void qkv_kernel(
    const float* __restrict__ h,
    const float* __restrict__ WQ, const float* __restrict__ bQ,
    const float* __restrict__ WK, const float* __restrict__ bK,
    const float* __restrict__ WV, const float* __restrict__ bV,
    unsigned short* __restrict__ Qb, unsigned short* __restrict__ Kb,
    float* __restrict__ V, int n_nodes)
{
    const int lane = threadIdx.x & 63;
    const int r16  = lane & 15;
    const int g4   = lane >> 4;
    const int wave   = blockIdx.x * (blockDim.x >> 6) + (threadIdx.x >> 6);
    const int nwaves = gridDim.x * (blockDim.x >> 6);
    const int mat  = blockIdx.y;

    const float* __restrict__ W  = (mat == 0) ? WQ : (mat == 1) ? WK : WV;
    const float* __restrict__ bp = (mat == 0) ? bQ : (mat == 1) ? bK : bV;

    bf16x8 bfr[4][4];
#pragma unroll
    for (int ct = 0; ct < 4; ++ct)
#pragma unroll
        for (int kc = 0; kc < 4; ++kc)
#pragma unroll
            for (int j = 0; j < 8; ++j) {
                int k = kc * 32 + g4 * 8 + j;
                bfr[ct][kc][j] = f2bf(W[k * HID + ct * 16 + r16]);
            }
    float bias[4];
#pragma unroll
    for (int ct = 0; ct < 4; ++ct) bias[ct] = bp[ct * 16 + r16];

    const float SC = 0.35355339059327373f;
    const int ntiles = (n_nodes + 15) >> 4;
    for (int tile = wave; tile < ntiles; tile += nwaves) {
        const int row0 = tile * 16;
        int arow = row0 + r16; if (arow > n_nodes - 1) arow = n_nodes - 1;
        const float* ap = h + (size_t)arow * IN_NODE + g4 * 8;

        bf16x8 afr[4];
#pragma unroll
        for (int kc = 0; kc < 4; ++kc) {
            f32x4 p0 = *reinterpret_cast<const f32x4*>(ap + kc * 32);
            f32x4 p1 = *reinterpret_cast<const f32x4*>(ap + kc * 32 + 4);
            afr[kc][0] = f2bf(p0.x); afr[kc][1] = f2bf(p0.y);
            afr[kc][2] = f2bf(p0.z); afr[kc][3] = f2bf(p0.w);
            afr[kc][4] = f2bf(p1.x); afr[kc][5] = f2bf(p1.y);
            afr[kc][6] = f2bf(p1.z); afr[kc][7] = f2bf(p1.w);
        }

        f32x4 acc[4] = {};
#pragma unroll
        for (int ct = 0; ct < 4; ++ct)
#pragma unroll
            for (int kc = 0; kc < 4; ++kc)
                acc[ct] = __builtin_amdgcn_mfma_f32_16x16x32_bf16(
                    afr[kc], bfr[ct][kc], acc[ct], 0, 0, 0);

#pragma unroll
        for (int ct = 0; ct < 4; ++ct)
#pragma unroll
            for (int r = 0; r < 4; ++r) {
                int orow = row0 + g4 * 4 + r;
                if (orow < n_nodes) {
                    float val = acc[ct][r] + bias[ct];
                    size_t idx = (size_t)orow * HID + ct * 16 + r16;
                    if (mat == 0)      Qb[idx] = (unsigned short)f2bf(val);
                    else if (mat == 1) Kb[idx] = (unsigned short)f2bf(val * SC);
                    else               V[idx]  = val;
                }
            }
    }
}

// ---------------------------------------------------------------------------
// Edge kernel, 2-tile pipelined: per iteration, ALL loads (e rows, indices,
// bf16 K/Q gathers) for two independent 16-edge tiles are issued first, then
// MFMA + LDS remap for both (double-buffered), one lgkmcnt barrier, then
// both epilogues. Halves per-tile exposed latency at constant bytes.
// ---------------------------------------------------------------------------
__global__ __launch_bounds__(256, 3) void edge_kernel(
    const int* __restrict__ ei, const float* __restrict__ e,
    const float* __restrict__ We, const float* __restrict__ be,
    const unsigned short* __restrict__ Qb, const unsigned short* __restrict__ Kb,
    float* __restrict__ e_out, float* __restrict__ z_sum,
    float* __restrict__ cnt, int n_edges, int tpw)
{
    const int lane = threadIdx.x & 63;
    const int wid  = threadIdx.x >> 6;
    const int r16  = lane & 15;
    const int g4   = lane >> 4;
    const int el   = lane >> 2;   // epilogue: edge-local 0..15
    const int qg   = lane & 3;    // epilogue: col-quad 0..3

    __shared__ float plds[4][2][16][LDSP];

    const int wave = blockIdx.x * 4 + wid;

    bf16x8 bfr[4][2];
#pragma unroll
    for (int ct = 0; ct < 4; ++ct)
#pragma unroll
        for (int kc = 0; kc < 2; ++kc)
#pragma unroll
            for (int j = 0; j < 8; ++j) {
                int k = kc * 32 + g4 * 8 + j;
                bfr[ct][kc][j] = f2bf(We[k * HID + ct * 16 + r16]);
            }
    float bias[4];
#pragma unroll
    for (int ct = 0; ct < 4; ++ct) bias[ct] = be[ct * 16 + r16];

    const int ntiles = (n_edges + 15) >> 4;
    int t0 = wave * tpw;
    int t1 = t0 + tpw; if (t1 > ntiles) t1 = ntiles;

    for (int t = t0; t < t1; t += 2) {
        // ================= phase L: all loads for both tiles =================
        f32x4 ev[2][4];
        int srcs[2], dsts[2];
        u32x4 kb[2][2], qb[2][2];
#pragma unroll
        for (int u = 0; u < 2; ++u) {
            int tt = t + u; if (tt > ntiles - 1) tt = ntiles - 1;
            int arow = tt * 16 + r16; if (arow > n_edges - 1) arow = n_edges - 1;
            const float* ap = e + (size_t)arow * IN_EDGE + g4 * 8;
            ev[u][0] = *reinterpret_cast<const f32x4*>(ap);
            ev[u][1] = *reinterpret_cast<const f32x4*>(ap + 4);
            ev[u][2] = *reinterpret_cast<const f32x4*>(ap + 32);
            ev[u][3] = *reinterpret_cast<const f32x4*>(ap + 36);

            int erc = tt * 16 + el; if (erc > n_edges - 1) erc = n_edges - 1;
            srcs[u] = ei[erc];
            dsts[u] = ei[n_edges + erc];
            const unsigned int* kp = reinterpret_cast<const unsigned int*>(Kb)
                                     + (size_t)srcs[u] * 32 + qg * 8;
            const unsigned int* qp = reinterpret_cast<const unsigned int*>(Qb)
                                     + (size_t)dsts[u] * 32 + qg * 8;
            kb[u][0] = *reinterpret_cast<const u32x4*>(kp);
            kb[u][1] = *reinterpret_cast<const u32x4*>(kp + 4);
            qb[u][0] = *reinterpret_cast<const u32x4*>(qp);
            qb[u][1] = *reinterpret_cast<const u32x4*>(qp + 4);
        }

        // ================= phase C: MFMA + LDS remap, both tiles =============
#pragma unroll
        for (int u = 0; u < 2; ++u) {
            bf16x8 afr[2];
            afr[0][0] = f2bf(ev[u][0].x); afr[0][1] = f2bf(ev[u][0].y);
            afr[0][2] = f2bf(ev[u][0].z); afr[0][3] = f2bf(ev[u][0].w);
            afr[0][4] = f2bf(ev[u][1].x); afr[0][5] = f2bf(ev[u][1].y);
            afr[0][6] = f2bf(ev[u][1].z); afr[0][7] = f2bf(ev[u][1].w);
            afr[1][0] = f2bf(ev[u][2].x); afr[1][1] = f2bf(ev[u][2].y);
            afr[1][2] = f2bf(ev[u][2].z); afr[1][3] = f2bf(ev[u][2].w);
            afr[1][4] = f2bf(ev[u][3].x); afr[1][5] = f2bf(ev[u][3].y);
            afr[1][6] = f2bf(ev[u][3].z); afr[1][7] = f2bf(ev[u][3].w);

            f32x4 acc[4] = {};
#pragma unroll
            for (int ct = 0; ct < 4; ++ct) {
                acc[ct] = __builtin_amdgcn_mfma_f32_16x16x32_bf16(afr[0], bfr[ct][0], acc[ct], 0, 0, 0);
                acc[ct] = __builtin_amdgcn_mfma_f32_16x16x32_bf16(afr[1], bfr[ct][1], acc[ct], 0, 0, 0);
            }
#pragma unroll
            for (int ct = 0; ct < 4; ++ct)
#pragma unroll
                for (int r = 0; r < 4; ++r)
                    plds[wid][u][g4 * 4 + r][ct * 16 + r16] = acc[ct][r] + bias[ct];
        }

        // one cross-lane LDS handoff per pair
        asm volatile("s_waitcnt lgkmcnt(0)" ::: "memory");

        // ================= phase E: epilogues, both tiles ====================
#pragma unroll
        for (int u = 0; u < 2; ++u) {
            const int tt = t + u;
            const int erow = tt * 16 + el;
            const bool valid = (tt < t1) && (erow < n_edges);

            const float* mrow = &plds[wid][u][el][qg * 16];
            f32x4 p0 = *reinterpret_cast<const f32x4*>(mrow);
            f32x4 p1 = *reinterpret_cast<const f32x4*>(mrow + 4);
            f32x4 p2 = *reinterpret_cast<const f32x4*>(mrow + 8);
            f32x4 p3 = *reinterpret_cast<const f32x4*>(mrow + 12);
            float pe[16];
            pe[0]=p0.x; pe[1]=p0.y; pe[2]=p0.z; pe[3]=p0.w;
            pe[4]=p1.x; pe[5]=p1.y; pe[6]=p1.z; pe[7]=p1.w;
            pe[8]=p2.x; pe[9]=p2.y; pe[10]=p2.z; pe[11]=p2.w;
            pe[12]=p3.x; pe[13]=p3.y; pe[14]=p3.z; pe[15]=p3.w;

            float sc[16];
#pragma unroll
            for (int half = 0; half < 2; ++half)
#pragma unroll
                for (int w = 0; w < 4; ++w) {
                    unsigned ku = kb[u][half][w];
                    unsigned qu = qb[u][half][w];
                    int c = half * 8 + 2 * w;
                    sc[c]     = fmaf(bflo(ku), bflo(qu), pe[c]);
                    sc[c + 1] = fmaf(bfhi(ku), bfhi(qu), pe[c + 1]);
                }

            if (valid) {
                float* op = e_out + (size_t)erow * HID + qg * 16;
                f32x4 s0 = {sc[0], sc[1], sc[2], sc[3]};
                f32x4 s1 = {sc[4], sc[5], sc[6], sc[7]};
                f32x4 s2 = {sc[8], sc[9], sc[10], sc[11]};
                f32x4 s3 = {sc[12], sc[13], sc[14], sc[15]};
                *reinterpret_cast<f32x4*>(op)      = s0;
                *reinterpret_cast<f32x4*>(op + 4)  = s1;
                *reinterpret_cast<f32x4*>(op + 8)  = s2;
                *reinterpret_cast<f32x4*>(op + 12) = s3;
            }

            float hs0 = ((sc[0] + sc[1]) + (sc[2] + sc[3])) + ((sc[4] + sc[5]) + (sc[6] + sc[7]));
            float hs1 = ((sc[8] + sc[9]) + (sc[10] + sc[11])) + ((sc[12] + sc[13]) + (sc[14] + sc[15]));
            float a0 = __expf(fminf(fmaxf(hs0, -5.0f), 5.0f));
            float a1 = __expf(fminf(fmaxf(hs1, -5.0f), 5.0f));
            if (valid) {
                atomicAdd(&z_sum[srcs[u] * HEADS + qg * 2], a0);
                atomicAdd(&z_sum[srcs[u] * HEADS + qg * 2 + 1], a1);
                if (qg == 0) atomicAdd(&cnt[srcs[u]], 1.0f);
            }
        }
    }
}

// ---------------------------------------------------------------------------
// Finalize: h_out[n,h,d] = V[n,h,d]*S / (S/max(cnt,1) + 1e-6)
// ---------------------------------------------------------------------------
__global__ __launch_bounds__(256) void finalize_kernel(
    const float* __restrict__ V, const float* __restrict__ z_sum,
    const float* __restrict__ cnt, float* __restrict__ h_out, int total)
{
    int i = blockIdx.x * 256 + threadIdx.x;
    if (i >= total) return;
    int node = i >> 6;
    int head = (i >> 3) & 7;
    float S = z_sum[node * HEADS + head];
    float c = fmaxf(cnt[node], 1.0f);
    h_out[i] = V[i] * S / (S / c + 1e-6f);
}

extern "C" void kernel_launch(void* const* d_in, const int* in_sizes, int n_in,
                              void* d_out, int out_size, void* d_ws, size_t ws_size,
                              hipStream_t stream)
{
    const int*   ei = (const int*)d_in[0];
    const float* h  = (const float*)d_in[1];
    const float* e  = (const float*)d_in[2];
    const float* WQ = (const float*)d_in[3];
    const float* bQ = (const float*)d_in[4];
    const float* WK = (const float*)d_in[5];
    const float* bK = (const float*)d_in[6];
    const float* WV = (const float*)d_in[7];
    const float* bV = (const float*)d_in[8];
    const float* We = (const float*)d_in[9];
    const float* be = (const float*)d_in[10];

    const int n_nodes = in_sizes[1] / IN_NODE;   // 50000
    const int n_edges = in_sizes[2] / IN_EDGE;   // 800000

    float* out_h = (float*)d_out;                       // n_nodes*64
    float* out_e = out_h + (size_t)n_nodes * HID;       // n_edges*64

    unsigned short* Qb = (unsigned short*)d_ws;          // bf16, n*64
    unsigned short* Kb = Qb + (size_t)n_nodes * HID;     // bf16 (pre-scaled)
    float* V     = (float*)(Kb + (size_t)n_nodes * HID);
    float* z_sum = V + (size_t)n_nodes * HID;
    float* cnt   = z_sum + (size_t)n_nodes * HEADS;

    (void)hipMemsetAsync(z_sum, 0, (size_t)n_nodes * (HEADS + 1) * sizeof(float), stream);

    // QKV: 96 blocks x 4 waves x 3 mats
    {
        dim3 grid(96, 3);
        qkv_kernel<<<grid, 256, 0, stream>>>(h, WQ, bQ, WK, bK, WV, bV,
                                             Qb, Kb, V, n_nodes);
    }
    // Edge: 2500 blocks x 4 waves = 10000 waves x exactly 5 tiles
    {
        const int nblk = 2500;
        const int nwaves = nblk * 4;
        const int ntiles = (n_edges + 15) >> 4;
        const int tpw = (ntiles + nwaves - 1) / nwaves;
        edge_kernel<<<nblk, 256, 0, stream>>>(ei, e, We, be, Qb, Kb,
                                              out_e, z_sum, cnt, n_edges, tpw);
    }
    // Finalize
    {
        const int total = n_nodes * HID;
        finalize_kernel<<<(total + 255) / 256, 256, 0, stream>>>(V, z_sum, cnt,
                                                                 out_h, total);
    }
}